// Round 1
// baseline (873.117 us; speedup 1.0000x reference)
//
#include <hip/hip_runtime.h>
#include <math.h>

#define NZTOT   262144
#define MF      131072      /* NZTOT/2 */
#define KCUT    62584       /* first k with g_sq clamped to 1 is 62583; include it (value ~0) */
#define KWS     62592       /* padded stride for w_tilde */
#define DZ_F    0.1f
#define GC_F    15.0f

__device__ __forceinline__ int rev256(int k) {
  return ((k & 3) << 6) | (((k >> 2) & 3) << 4) | (((k >> 4) & 3) << 2) | ((k >> 6) & 3);
}
__device__ __forceinline__ int rev512(int k) {
  return ((k & 3) << 7) | (((k >> 2) & 3) << 5) | (((k >> 4) & 3) << 3) |
         (((k >> 6) & 3) << 1) | ((k >> 8) & 1);
}

// In-LDS radix-4 DIF FFT over one contiguous line of L complex values.
// TPL threads per line, p = thread index within line. Output is digit-reversed.
template<int L, int TPL, int SIGN>
__device__ __forceinline__ void dif_fft_line(float2* v, int p) {
  #pragma unroll
  for (int s = 0; (L >> (2 * s)) >= 4; ++s) {
    const int B = L >> (2 * s);
    const int Q = B >> 2;
    #pragma unroll
    for (int it = 0; it < (L / 4) / TPL; ++it) {
      int i = p + it * TPL;
      int g = i / Q;
      int j = i - g * Q;
      int base = g * B + j;
      float2 a0 = v[base], a1 = v[base + Q], a2 = v[base + 2 * Q], a3 = v[base + 3 * Q];
      float t0x = a0.x + a2.x, t0y = a0.y + a2.y;
      float t1x = a0.x - a2.x, t1y = a0.y - a2.y;
      float t2x = a1.x + a3.x, t2y = a1.y + a3.y;
      float dx = a1.x - a3.x, dy = a1.y - a3.y;
      float t3x = -(float)SIGN * dy, t3y = (float)SIGN * dx;   /* sign*i*(a1-a3) */
      float y0x = t0x + t2x, y0y = t0y + t2y;
      float y2x = t0x - t2x, y2y = t0y - t2y;
      float y1x = t1x + t3x, y1y = t1y + t3y;
      float y3x = t1x - t3x, y3y = t1y - t3y;
      float s1, c1;
      sincospif((float)SIGN * 2.0f * (float)j / (float)B, &s1, &c1);
      float c2 = c1 * c1 - s1 * s1, s2 = 2.0f * c1 * s1;
      float c3 = c1 * c2 - s1 * s2, s3 = c1 * s2 + s1 * c2;
      v[base] = make_float2(y0x, y0y);
      v[base + Q]     = make_float2(y1x * c1 - y1y * s1, y1x * s1 + y1y * c1);
      v[base + 2 * Q] = make_float2(y2x * c2 - y2y * s2, y2x * s2 + y2y * c2);
      v[base + 3 * Q] = make_float2(y3x * c3 - y3y * s3, y3x * s3 + y3y * c3);
    }
    __syncthreads();
  }
  if (L == 512) {  /* trailing radix-2 stage */
    #pragma unroll
    for (int it = 0; it < (L / 2) / TPL; ++it) {
      int i = p + it * TPL;
      float2 a0 = v[2 * i], a1 = v[2 * i + 1];
      v[2 * i]     = make_float2(a0.x + a1.x, a0.y + a1.y);
      v[2 * i + 1] = make_float2(a0.x - a1.x, a0.y - a1.y);
    }
    __syncthreads();
  }
}

// Four-step stage 1: for each n1 in [0,512): length-256 DFT over n2 (input stride 512),
// apply twiddle e^{SIGN*2pi*i*n1*k2/M}, write transposed G[k2*512 + n1] (natural k2).
template<int SIGN>
__global__ __launch_bounds__(256) void k_fft_stage1(const float2* __restrict__ gin,
                                                    float2* __restrict__ gout) {
  __shared__ float2 tile[16][258];
  const float2* in = gin + (size_t)blockIdx.y * MF;
  float2* out = gout + (size_t)blockIdx.y * MF;
  int c16 = blockIdx.x * 16;
  int tx = threadIdx.x & 15, ty = threadIdx.x >> 4;
  #pragma unroll
  for (int j = 0; j < 16; ++j) {
    int n2 = ty + j * 16;
    tile[tx][n2] = in[(size_t)n2 * 512 + c16 + tx];
  }
  __syncthreads();
  dif_fft_line<256, 16, SIGN>(&tile[ty][0], tx);
  int n1 = c16 + tx;
  #pragma unroll
  for (int u = 0; u < 16; ++u) {
    int k2 = ty + u * 16;
    float2 vv = tile[tx][rev256(k2)];
    float s1, c1;
    sincospif((float)SIGN * 2.0f * (float)(n1 * k2) / (float)MF, &s1, &c1);
    out[(size_t)k2 * 512 + n1] = make_float2(vv.x * c1 - vv.y * s1, vv.x * s1 + vv.y * c1);
  }
}

// Four-step stage 2: for each k2: length-512 DFT over n1 (contiguous line in G).
// UNPERM=true  -> write natural order X[k1*256 + k2] (needed for spectral multiply)
// UNPERM=false -> write digit-reversed in-place order (order-agnostic consumer)
template<int SIGN, bool UNPERM>
__global__ __launch_bounds__(256) void k_fft_stage2(const float2* __restrict__ gin,
                                                    float2* __restrict__ gout) {
  __shared__ float2 tile[8][514];
  const float2* in = gin + (size_t)blockIdx.y * MF;
  float2* out = gout + (size_t)blockIdx.y * MF;
  int c8 = blockIdx.x * 8;
  #pragma unroll
  for (int j = 0; j < 16; ++j) {
    int flat = threadIdx.x + 256 * j;
    tile[flat >> 9][flat & 511] = in[(size_t)c8 * 512 + flat];
  }
  __syncthreads();
  dif_fft_line<512, 32, SIGN>(&tile[threadIdx.x >> 5][0], threadIdx.x & 31);
  if (UNPERM) {
    int sx = threadIdx.x & 7, sy = threadIdx.x >> 3;
    #pragma unroll
    for (int u = 0; u < 16; ++u) {
      int k1 = sy + 32 * u;
      out[(size_t)k1 * 256 + c8 + sx] = tile[sx][rev512(k1)];
    }
  } else {
    #pragma unroll
    for (int j = 0; j < 16; ++j) {
      int flat = threadIdx.x + 256 * j;
      out[(size_t)c8 * 512 + flat] = tile[flat >> 9][flat & 511];
    }
  }
}

// w_tilde[c][k] for k < KCUT (zero beyond cutoff, never stored/read there).
__global__ __launch_bounds__(256) void k_wtilde(
    const float* __restrict__ W0, const float* __restrict__ b0,
    const float* __restrict__ W1, const float* __restrict__ b1,
    const float* __restrict__ W2, const float* __restrict__ b2,
    float2* __restrict__ wt) {
  int k = blockIdx.x * 256 + threadIdx.x;
  if (k >= KCUT) return;
  const float GZSC = (float)(2.0 * 3.14159265358979323846 / 26214.4);
  float Gz = (float)k * GZSC;
  float g = Gz / GC_F;
  float gsq = fminf(g * g, 1.0f);
  float h1[64], h2[64];
  #pragma unroll
  for (int o = 0; o < 64; ++o) {
    float x = W0[o] * gsq + b0[o];
    h1[o] = x > 0.0f ? x : expm1f(x);
  }
  #pragma unroll
  for (int o = 0; o < 64; ++o) {
    float acc = b1[o];
    #pragma unroll
    for (int i = 0; i < 64; ++i) acc = fmaf(W1[o * 64 + i], h1[i], acc);
    h2[o] = acc > 0.0f ? acc : expm1f(acc);
  }
  float om = 1.0f - gsq;
  float fac2 = om * om;
  #pragma unroll
  for (int c = 0; c < 8; ++c) {
    float acc = b2[c];
    #pragma unroll
    for (int i = 0; i < 64; ++i) acc = fmaf(W2[c * 64 + i], h2[i], acc);
    const int P = c & 3;
    float gp = 1.0f;
    #pragma unroll
    for (int t = 0; t < P; ++t) gp *= gsq;
    const int GP = 2 * P + (c >= 4 ? 1 : 0);
    float prod = 1.0f;
    #pragma unroll
    for (int t = 0; t < 5; ++t) prod *= (float)(2 * GP + 2 * t + 1);
    float nrm = sqrtf(prod / 384.0f);
    if (c >= 4) nrm *= (1.0f / GC_F);
    float wv = acc * fac2 * gp * nrm;
    float2 z = (c < 4) ? make_float2(wv, 0.0f) : make_float2(0.0f, Gz * wv);
    wt[(size_t)c * KWS + k] = z;
  }
}

// Unpack rfft from packed forward FFT C, multiply by w_tilde, and re-pack the
// product spectrum for the packed inverse transform (includes 0.5/M scaling).
// Exploits Y[k]=0 for k>=KCUT (so the conj-partner term vanishes for k<=M/2).
__global__ __launch_bounds__(256) void k_specmul(const float2* __restrict__ C,
                                                 const float2* __restrict__ wt,
                                                 float2* __restrict__ Z) {
  int k = blockIdx.x * 256 + threadIdx.x;
  if (k > MF / 2) return;
  int b = blockIdx.y;
  const float2* Cb = C + (size_t)b * MF;
  const float SCL = 0.5f / (float)MF;
  if (k < KCUT) {
    float2 Ck = Cb[k];
    float2 Cm = Cb[(MF - k) & (MF - 1)];
    float sE, cE;
    sincospif((float)k * (1.0f / 131072.0f), &sE, &cE);   /* E = e^{2*pi*i*k/N} */
    float Ax = Ck.x + Cm.x, Ay = Ck.y - Cm.y;
    float Dx = Ck.x - Cm.x, Dy = Ck.y + Cm.y;
    float tx = cE * Dx + sE * Dy;
    float ty = cE * Dy - sE * Dx;
    float Xx = 0.5f * (Ax + ty);     /* X[k] = rfft(n)[k] */
    float Xy = 0.5f * (Ay - tx);
    float F1x = 1.0f - sE, F2x = 1.0f + sE;
    #pragma unroll
    for (int f = 0; f < 8; ++f) {
      float2 w = wt[(size_t)f * KWS + k];
      float Yx = w.x * Xx - w.y * Xy;
      float Yy = w.x * Xy + w.y * Xx;
      size_t base = ((size_t)(f * 8 + b)) * MF;
      Z[base + k] = make_float2(SCL * (Yx * F1x - Yy * cE), SCL * (Yx * cE + Yy * F1x));
      if (k > 0)
        Z[base + MF - k] = make_float2(SCL * (Yx * F2x + Yy * cE), SCL * (Yx * cE - Yy * F2x));
    }
  } else {
    #pragma unroll
    for (int f = 0; f < 8; ++f) {
      size_t base = ((size_t)(f * 8 + b)) * MF;
      Z[base + k] = make_float2(0.0f, 0.0f);
      Z[base + MF - k] = make_float2(0.0f, 0.0f);
    }
  }
}

// Pointwise: 14 scalars -> MLP -> weighted sum; block partial sums per batch.
__global__ __launch_bounds__(256) void k_mlpsum(
    const float* __restrict__ conv,
    const float* __restrict__ W0, const float* __restrict__ b0,
    const float* __restrict__ W1, const float* __restrict__ b1,
    const float* __restrict__ W2, const float* __restrict__ b2,
    float* __restrict__ partial) {
  int b = blockIdx.y;
  size_t z = (size_t)blockIdx.x * 256 + threadIdx.x;
  float sc[14];
  #pragma unroll
  for (int c = 0; c < 4; ++c) sc[c] = conv[(size_t)(c * 8 + b) * NZTOT + z];
  float o0 = conv[(size_t)(4 * 8 + b) * NZTOT + z];
  float o1 = conv[(size_t)(5 * 8 + b) * NZTOT + z];
  float o2 = conv[(size_t)(6 * 8 + b) * NZTOT + z];
  float o3 = conv[(size_t)(7 * 8 + b) * NZTOT + z];
  sc[4] = o0 * o0; sc[5] = o0 * o1; sc[6] = o0 * o2; sc[7] = o0 * o3;
  sc[8] = o1 * o1; sc[9] = o1 * o2; sc[10] = o1 * o3;
  sc[11] = o2 * o2; sc[12] = o2 * o3;
  sc[13] = o3 * o3;
  float h1[64];
  #pragma unroll
  for (int o = 0; o < 64; ++o) {
    float acc = b0[o];
    #pragma unroll
    for (int i = 0; i < 14; ++i) acc = fmaf(W0[o * 14 + i], sc[i], acc);
    h1[o] = acc > 0.0f ? acc : expm1f(acc);
  }
  float h2[64];
  #pragma unroll
  for (int o = 0; o < 64; ++o) {
    float acc = b1[o];
    #pragma unroll
    for (int i = 0; i < 64; ++i) acc = fmaf(W1[o * 64 + i], h1[i], acc);
    h2[o] = acc > 0.0f ? acc : expm1f(acc);
  }
  float tot = 0.0f;
  #pragma unroll
  for (int c = 0; c < 14; ++c) {
    float acc = b2[c];
    #pragma unroll
    for (int i = 0; i < 64; ++i) acc = fmaf(W2[c * 64 + i], h2[i], acc);
    tot += sc[c] * acc;
  }
  __shared__ float red[256];
  red[threadIdx.x] = tot;
  __syncthreads();
  for (int s = 128; s > 0; s >>= 1) {
    if (threadIdx.x < s) red[threadIdx.x] += red[threadIdx.x + s];
    __syncthreads();
  }
  if (threadIdx.x == 0) partial[b * 1024 + blockIdx.x] = red[0];
}

__global__ __launch_bounds__(256) void k_reduce(const float* __restrict__ partial,
                                                float* __restrict__ out) {
  __shared__ float red[256];
  int b = blockIdx.x;
  float acc = 0.0f;
  #pragma unroll
  for (int j = 0; j < 4; ++j) acc += partial[b * 1024 + threadIdx.x + 256 * j];
  red[threadIdx.x] = acc;
  __syncthreads();
  for (int s = 128; s > 0; s >>= 1) {
    if (threadIdx.x < s) red[threadIdx.x] += red[threadIdx.x + s];
    __syncthreads();
  }
  if (threadIdx.x == 0) out[b] = DZ_F * red[0];
}

extern "C" void kernel_launch(void* const* d_in, const int* in_sizes, int n_in,
                              void* d_out, int out_size, void* d_ws, size_t ws_size,
                              hipStream_t stream) {
  (void)in_sizes; (void)n_in; (void)out_size; (void)ws_size;
  const float2* nP = (const float2*)d_in[0];   /* n viewed as packed complex, per batch MF */
  const float* wW0 = (const float*)d_in[1];
  const float* wb0 = (const float*)d_in[2];
  const float* wW1 = (const float*)d_in[3];
  const float* wb1 = (const float*)d_in[4];
  const float* wW2 = (const float*)d_in[5];
  const float* wb2 = (const float*)d_in[6];
  const float* fW0 = (const float*)d_in[7];
  const float* fb0 = (const float*)d_in[8];
  const float* fW1 = (const float*)d_in[9];
  const float* fb1 = (const float*)d_in[10];
  const float* fW2 = (const float*)d_in[11];
  const float* fb2 = (const float*)d_in[12];

  /* workspace layout (float2 units): Gf[8*MF] | C[8*MF] | wt[8*KWS] | Z[64*MF] | T[64*MF] | partial */
  float2* Gf = (float2*)d_ws;
  float2* C  = Gf + (size_t)8 * MF;
  float2* wt = C + (size_t)8 * MF;
  float2* Z  = wt + (size_t)8 * KWS;
  float2* T  = Z + (size_t)64 * MF;
  float*  partial = (float*)(T + (size_t)64 * MF);
  float*  conv = (float*)Z;   /* conv aliases Z: Z fully consumed by inverse stage 1 */

  k_wtilde<<<dim3((KCUT + 255) / 256), dim3(256), 0, stream>>>(wW0, wb0, wW1, wb1, wW2, wb2, wt);
  k_fft_stage1<(-1)><<<dim3(32, 8), dim3(256), 0, stream>>>(nP, Gf);
  k_fft_stage2<(-1), true><<<dim3(32, 8), dim3(256), 0, stream>>>(Gf, C);
  k_specmul<<<dim3(257, 8), dim3(256), 0, stream>>>(C, wt, Z);
  k_fft_stage1<1><<<dim3(32, 64), dim3(256), 0, stream>>>(Z, T);
  k_fft_stage2<1, false><<<dim3(32, 64), dim3(256), 0, stream>>>(T, (float2*)conv);
  k_mlpsum<<<dim3(1024, 8), dim3(256), 0, stream>>>(conv, fW0, fb0, fW1, fb1, fW2, fb2, partial);
  k_reduce<<<dim3(8), dim3(256), 0, stream>>>(partial, (float*)d_out);
}